// Round 2
// baseline (1410.323 us; speedup 1.0000x reference)
//
#include <hip/hip_runtime.h>
#include <hip/hip_bf16.h>

// HetNetwork fused 3-layer MLP (gfx950). I/O is fp32 (per reference);
// compute is bf16 MFMA (harness tolerance 2% / floor_eps_k=8 budgets this).
// Layer dims: [B,1024] -> 256 -> 256 -> 256, B=131072.
// One fused kernel: 64 rows/block, h1/h2 kept in LDS, weights pre-transposed
// + converted to bf16 [N][K] in d_ws by a prep kernel.

typedef __bf16 bf16;
typedef __bf16 bf16x8 __attribute__((ext_vector_type(8)));
typedef float  f32x4  __attribute__((ext_vector_type(4)));

#define BATCH 131072
#define K1    1024
#define HDIM  256
#define RM    64      // rows per block
#define BK    32      // k-tile
#define APAD  40      // as row stride (bf16): 32 + 8 pad
#define WPAD  40      // ws row stride
#define HPAD  264     // hs row stride: 256 + 8 pad (528 B, 16B-aligned)

// ---- per-column heterogeneous activation (exact forms) ----
__device__ __forceinline__ float het_act(float z, int aid) {
    if (aid == 0) return fmaxf(z, 0.0f);
    if (aid == 1) {
        float zc = fminf(fmaxf(z, -20.0f), 20.0f);     // keep expf finite
        float e = __expf(-2.0f * zc);
        return (1.0f - e) / (1.0f + e);                // tanh
    }
    if (aid == 2) return 0.5f * z * (1.0f + erff(z * 0.70710678118654752f)); // exact gelu
    return 1.0f / (1.0f + __expf(-z));                 // sigmoid
}

// ---- prep: dst[n][k] = (bf16)src[k][n]. i = n*K + k (coalesced writes) ----
__global__ void prep_w(const float* __restrict__ src, bf16* __restrict__ dst,
                       int total, int kshift, int N) {
    int i = blockIdx.x * blockDim.x + threadIdx.x;
    if (i >= total) return;
    int n = i >> kshift;
    int k = i & ((1 << kshift) - 1);
    dst[i] = (bf16)src[(size_t)k * N + n];
}

__global__ __launch_bounds__(256, 2) void hetnet_fused(
    const float* __restrict__ x,    // [B][1024] fp32
    const bf16*  __restrict__ wt1,  // [256][1024]  = bf16(W1^T)
    const float* __restrict__ b1,
    const bf16*  __restrict__ wt2,  // [256][256]   = bf16(W2^T)
    const float* __restrict__ b2,
    const bf16*  __restrict__ wt3,  // [256][256]   = bf16(Wout^T)
    const float* __restrict__ bout,
    const int*   __restrict__ aid1,
    const int*   __restrict__ aid2,
    float* __restrict__ out)        // [B][256] fp32
{
    __shared__ __align__(16) bf16 hs[RM][HPAD];    // h1 / h2 tile   (33792 B)
    __shared__ __align__(16) bf16 as[RM][APAD];    // x k-tile       ( 5120 B)
    __shared__ __align__(16) bf16 ws[HDIM][WPAD];  // W k-tile       (20480 B)

    const int tid  = threadIdx.x;
    const int lane = tid & 63;
    const int wave = tid >> 6;       // 0..3 -> 64-col slab
    const int l15  = lane & 15;
    const int quad = lane >> 4;      // 0..3
    const size_t row0 = (size_t)blockIdx.x * RM;

    f32x4 acc[4][4];

    // ================= GEMM1: hs = act(x @ W1 + b1) =================
    #pragma unroll
    for (int i = 0; i < 4; ++i)
        #pragma unroll
        for (int j = 0; j < 4; ++j)
            acc[i][j] = (f32x4){0.f, 0.f, 0.f, 0.f};

    for (int kt = 0; kt < K1 / BK; ++kt) {
        const int k0 = kt * BK;
        // stage x tile: 64 rows x 32 k fp32 -> bf16. 1 thread = 8 elems (2 float4)
        {
            int r = tid >> 2, q = tid & 3;
            const float* xp = x + (row0 + r) * K1 + k0 + q * 8;
            float4 f0 = *(const float4*)xp;
            float4 f1 = *(const float4*)(xp + 4);
            bf16x8 v;
            v[0] = (bf16)f0.x; v[1] = (bf16)f0.y; v[2] = (bf16)f0.z; v[3] = (bf16)f0.w;
            v[4] = (bf16)f1.x; v[5] = (bf16)f1.y; v[6] = (bf16)f1.z; v[7] = (bf16)f1.w;
            *(bf16x8*)&as[r][q * 8] = v;
        }
        // stage W1^T tile (already bf16): 256 n x 32 k = 1024 chunks, 4/thread
        #pragma unroll
        for (int p = 0; p < 4; ++p) {
            int c = tid + p * 256;
            int n = c >> 2, q = c & 3;
            *(bf16x8*)&ws[n][q * 8] =
                *(const bf16x8*)(wt1 + (size_t)n * K1 + k0 + q * 8);
        }
        __syncthreads();
        bf16x8 afr[4];
        #pragma unroll
        for (int i = 0; i < 4; ++i)
            afr[i] = *(const bf16x8*)&as[i * 16 + l15][quad * 8];
        #pragma unroll
        for (int j = 0; j < 4; ++j) {
            bf16x8 bfr = *(const bf16x8*)&ws[wave * 64 + j * 16 + l15][quad * 8];
            #pragma unroll
            for (int i = 0; i < 4; ++i)
                acc[i][j] = __builtin_amdgcn_mfma_f32_16x16x32_bf16(afr[i], bfr, acc[i][j], 0, 0, 0);
        }
        __syncthreads();
    }
    // epilogue 1: bias + per-col act, write bf16 into hs
    #pragma unroll
    for (int j = 0; j < 4; ++j) {
        int col = wave * 64 + j * 16 + l15;
        float bias = b1[col];
        int aid = aid1[col];
        #pragma unroll
        for (int i = 0; i < 4; ++i)
            #pragma unroll
            for (int r = 0; r < 4; ++r) {
                int row = i * 16 + quad * 4 + r;
                hs[row][col] = (bf16)het_act(acc[i][j][r] + bias, aid);
            }
    }
    // (visibility of hs ensured by the sync inside GEMM2's first k-step)

    // ================= GEMM2: hs = act(hs @ W2 + b2) =================
    #pragma unroll
    for (int i = 0; i < 4; ++i)
        #pragma unroll
        for (int j = 0; j < 4; ++j)
            acc[i][j] = (f32x4){0.f, 0.f, 0.f, 0.f};

    for (int kt = 0; kt < HDIM / BK; ++kt) {
        const int k0 = kt * BK;
        #pragma unroll
        for (int p = 0; p < 4; ++p) {
            int c = tid + p * 256;
            int n = c >> 2, q = c & 3;
            *(bf16x8*)&ws[n][q * 8] =
                *(const bf16x8*)(wt2 + (size_t)n * HDIM + k0 + q * 8);
        }
        __syncthreads();
        bf16x8 afr[4];
        #pragma unroll
        for (int i = 0; i < 4; ++i)
            afr[i] = *(const bf16x8*)&hs[i * 16 + l15][k0 + quad * 8];
        #pragma unroll
        for (int j = 0; j < 4; ++j) {
            bf16x8 bfr = *(const bf16x8*)&ws[wave * 64 + j * 16 + l15][quad * 8];
            #pragma unroll
            for (int i = 0; i < 4; ++i)
                acc[i][j] = __builtin_amdgcn_mfma_f32_16x16x32_bf16(afr[i], bfr, acc[i][j], 0, 0, 0);
        }
        __syncthreads();
    }
    // epilogue 2: bias + act, overwrite hs with h2 (all waves past last read:
    // final __syncthreads of the kt loop is after every wave's last hs read)
    #pragma unroll
    for (int j = 0; j < 4; ++j) {
        int col = wave * 64 + j * 16 + l15;
        float bias = b2[col];
        int aid = aid2[col];
        #pragma unroll
        for (int i = 0; i < 4; ++i)
            #pragma unroll
            for (int r = 0; r < 4; ++r) {
                int row = i * 16 + quad * 4 + r;
                hs[row][col] = (bf16)het_act(acc[i][j][r] + bias, aid);
            }
    }

    // ================= GEMM3: out = hs @ Wout + bout =================
    #pragma unroll
    for (int i = 0; i < 4; ++i)
        #pragma unroll
        for (int j = 0; j < 4; ++j)
            acc[i][j] = (f32x4){0.f, 0.f, 0.f, 0.f};

    for (int kt = 0; kt < HDIM / BK; ++kt) {
        const int k0 = kt * BK;
        #pragma unroll
        for (int p = 0; p < 4; ++p) {
            int c = tid + p * 256;
            int n = c >> 2, q = c & 3;
            *(bf16x8*)&ws[n][q * 8] =
                *(const bf16x8*)(wt3 + (size_t)n * HDIM + k0 + q * 8);
        }
        __syncthreads();
        bf16x8 afr[4];
        #pragma unroll
        for (int i = 0; i < 4; ++i)
            afr[i] = *(const bf16x8*)&hs[i * 16 + l15][k0 + quad * 8];
        #pragma unroll
        for (int j = 0; j < 4; ++j) {
            bf16x8 bfr = *(const bf16x8*)&ws[wave * 64 + j * 16 + l15][quad * 8];
            #pragma unroll
            for (int i = 0; i < 4; ++i)
                acc[i][j] = __builtin_amdgcn_mfma_f32_16x16x32_bf16(afr[i], bfr, acc[i][j], 0, 0, 0);
        }
        __syncthreads();
    }
    // epilogue 3: bias, store fp32 to global
    #pragma unroll
    for (int j = 0; j < 4; ++j) {
        int col = wave * 64 + j * 16 + l15;
        float bias = bout[col];
        #pragma unroll
        for (int i = 0; i < 4; ++i)
            #pragma unroll
            for (int r = 0; r < 4; ++r) {
                int row = i * 16 + quad * 4 + r;
                out[(row0 + row) * HDIM + col] = acc[i][j][r] + bias;
            }
    }
}

extern "C" void kernel_launch(void* const* d_in, const int* in_sizes, int n_in,
                              void* d_out, int out_size, void* d_ws, size_t ws_size,
                              hipStream_t stream) {
    const float* x    = (const float*)d_in[0];
    const float* W1   = (const float*)d_in[1];   // [1024][256] fp32
    const float* b1   = (const float*)d_in[2];
    const float* W2   = (const float*)d_in[3];   // [256][256] fp32
    const float* b2   = (const float*)d_in[4];
    const float* Wout = (const float*)d_in[5];   // [256][256] fp32
    const float* bout = (const float*)d_in[6];
    const int*   aid1 = (const int*)d_in[7];
    const int*   aid2 = (const int*)d_in[8];
    float* out = (float*)d_out;

    // workspace: transposed bf16 weights (768 KB total)
    bf16* wt1 = (bf16*)d_ws;             // 256*1024
    bf16* wt2 = wt1 + 256 * 1024;        // 256*256
    bf16* wt3 = wt2 + 256 * 256;         // 256*256

    prep_w<<<(K1 * HDIM + 255) / 256, 256, 0, stream>>>(W1, wt1, K1 * HDIM, 10, HDIM);
    prep_w<<<(HDIM * HDIM + 255) / 256, 256, 0, stream>>>(W2, wt2, HDIM * HDIM, 8, HDIM);
    prep_w<<<(HDIM * HDIM + 255) / 256, 256, 0, stream>>>(Wout, wt3, HDIM * HDIM, 8, HDIM);

    hetnet_fused<<<BATCH / RM, 256, 0, stream>>>(x, wt1, b1, wt2, b2, wt3, bout,
                                                 aid1, aid2, out);
}

// Round 3
// 991.163 us; speedup vs baseline: 1.4229x; 1.4229x over previous
//
#include <hip/hip_runtime.h>
#include <hip/hip_bf16.h>

// HetNetwork 3-layer MLP (gfx950), fp32 I/O, bf16 MFMA compute.
// [B,1024] -> 256 -> 256 -> 256, B=131072.
// Split structure: kernel A = GEMM1 (K=1024, 2/3 of FLOPs) at high occupancy,
// h1 round-trips global as bf16 (67 MB ~ 21 us HBM); kernel B = fused GEMM2+3.
// Rationale: fused-everything forces 59KB LDS -> 8 waves/CU -> latency-bound
// (R2: MfmaUtil 4.8%, occ 24%). Split gets 16 waves/CU on the dominant GEMM.

typedef __bf16 bf16;
typedef __bf16 bf16x8 __attribute__((ext_vector_type(8)));
typedef float  f32x4  __attribute__((ext_vector_type(4)));

#define BATCH 131072
#define K1    1024
#define HDIM  256

// ---- per-column heterogeneous activation (exact forms) ----
__device__ __forceinline__ float het_act(float z, int aid) {
    if (aid == 0) return fmaxf(z, 0.0f);
    if (aid == 1) {
        float zc = fminf(fmaxf(z, -20.0f), 20.0f);
        float e = __expf(-2.0f * zc);
        return (1.0f - e) / (1.0f + e);                // tanh
    }
    if (aid == 2) return 0.5f * z * (1.0f + erff(z * 0.70710678118654752f)); // exact gelu
    return 1.0f / (1.0f + __expf(-z));                 // sigmoid
}

// ---- prep: dst[n][k] = (bf16)src[k][n] ----
__global__ void prep_w(const float* __restrict__ src, bf16* __restrict__ dst,
                       int total, int kshift, int N) {
    int i = blockIdx.x * blockDim.x + threadIdx.x;
    if (i >= total) return;
    int n = i >> kshift;
    int k = i & ((1 << kshift) - 1);
    dst[i] = (bf16)src[(size_t)k * N + n];
}

// =====================================================================
// Kernel A: h1 = act(x @ W1 + b1)  [fp32 in, bf16 out]
// 128 rows x 256 cols per block, 512 threads = 8 waves (2 row-groups x 4 slabs)
// BK=64 -> 16 k-iterations, 32 MFMA per wave per barrier pair.
// =====================================================================
#define RMA 128
#define BKA 64
#define ASTR 72     // 64+8 pad: row step 144B = 36 banks -> 2-way (free)
#define HSTR 264    // h1-tile store stride

__global__ __launch_bounds__(512, 4) void gemm1_kernel(
    const float* __restrict__ x,    // [B][1024]
    const bf16*  __restrict__ wt1,  // [256][1024] bf16(W1^T)
    const float* __restrict__ b1,
    const int*   __restrict__ aid1,
    bf16* __restrict__ h1)          // [B][256] bf16
{
    // union: staging (as 18432 + ws 36864 = 55296 B) vs h1-tile (67584 B)
    __shared__ __align__(16) char smem[RMA * HSTR * 2];   // 67584 B
    bf16 (*as)[ASTR] = (bf16(*)[ASTR])smem;               // [128][72]
    bf16 (*ws)[ASTR] = (bf16(*)[ASTR])(smem + RMA * ASTR * 2); // [256][72]
    bf16 (*hout)[HSTR] = (bf16(*)[HSTR])smem;             // [128][264]

    const int tid  = threadIdx.x;
    const int lane = tid & 63;
    const int wave = tid >> 6;       // 0..7
    const int rg   = wave >> 2;      // row-group 0/1 (64 rows each)
    const int slab = wave & 3;       // 64-col slab
    const int l15  = lane & 15;
    const int quad = lane >> 4;
    const size_t row0 = (size_t)blockIdx.x * RMA;

    f32x4 acc[4][4];
    #pragma unroll
    for (int i = 0; i < 4; ++i)
        #pragma unroll
        for (int j = 0; j < 4; ++j)
            acc[i][j] = (f32x4){0.f, 0.f, 0.f, 0.f};

    for (int kt = 0; kt < K1 / BKA; ++kt) {
        const int k0 = kt * BKA;
        // stage x: 128r x 64k fp32 -> bf16. 1024 chunk8, 2/thread (8 float4 in flight)
        #pragma unroll
        for (int p = 0; p < 2; ++p) {
            int c = tid + p * 512;
            int r = c >> 3, q = c & 7;
            const float* xp = x + (row0 + r) * K1 + k0 + q * 8;
            float4 f0 = *(const float4*)xp;
            float4 f1 = *(const float4*)(xp + 4);
            bf16x8 v;
            v[0] = (bf16)f0.x; v[1] = (bf16)f0.y; v[2] = (bf16)f0.z; v[3] = (bf16)f0.w;
            v[4] = (bf16)f1.x; v[5] = (bf16)f1.y; v[6] = (bf16)f1.z; v[7] = (bf16)f1.w;
            *(bf16x8*)&as[r][q * 8] = v;
        }
        // stage W1^T: 256n x 64k bf16. 2048 chunk8, 4/thread
        #pragma unroll
        for (int p = 0; p < 4; ++p) {
            int c = tid + p * 512;
            int n = c >> 3, q = c & 7;
            *(bf16x8*)&ws[n][q * 8] =
                *(const bf16x8*)(wt1 + (size_t)n * K1 + k0 + q * 8);
        }
        __syncthreads();
        #pragma unroll
        for (int s = 0; s < 2; ++s) {
            bf16x8 afr[4];
            #pragma unroll
            for (int i = 0; i < 4; ++i)
                afr[i] = *(const bf16x8*)&as[rg * 64 + i * 16 + l15][s * 32 + quad * 8];
            #pragma unroll
            for (int j = 0; j < 4; ++j) {
                bf16x8 bfr = *(const bf16x8*)&ws[slab * 64 + j * 16 + l15][s * 32 + quad * 8];
                #pragma unroll
                for (int i = 0; i < 4; ++i)
                    acc[i][j] = __builtin_amdgcn_mfma_f32_16x16x32_bf16(afr[i], bfr, acc[i][j], 0, 0, 0);
            }
        }
        __syncthreads();
    }

    // epilogue: bias + act -> bf16 h1-tile in LDS (aliases staging; safe: all
    // frag ds_reads retired before the loop's final barrier)
    #pragma unroll
    for (int j = 0; j < 4; ++j) {
        int col = slab * 64 + j * 16 + l15;
        float bias = b1[col];
        int aid = aid1[col];
        #pragma unroll
        for (int i = 0; i < 4; ++i)
            #pragma unroll
            for (int r = 0; r < 4; ++r) {
                int row = rg * 64 + i * 16 + quad * 4 + r;
                hout[row][col] = (bf16)het_act(acc[i][j][r] + bias, aid);
            }
    }
    __syncthreads();
    // coalesced bf16x8 store: 128x256 = 4096 chunk8, 8/thread
    #pragma unroll
    for (int p = 0; p < 8; ++p) {
        int c = tid + p * 512;
        int r = c >> 5, q = c & 31;
        *(bf16x8*)(h1 + (row0 + r) * HDIM + q * 8) = *(const bf16x8*)&hout[r][q * 8];
    }
}

// =====================================================================
// Kernel B: out = act(h1 @ W2 + b2) @ Wout + bout   [bf16 in, fp32 out]
// 64 rows/block, 256 threads = 4 waves (col slabs). h1 tile loaded once.
// =====================================================================
#define RMB 64
#define BKB 64
#define BSTR 72
#define BHSTR 264

__global__ __launch_bounds__(256, 2) void gemm23_kernel(
    const bf16*  __restrict__ h1,   // [B][256] bf16
    const bf16*  __restrict__ wt2,  // [256][256] bf16(W2^T)
    const float* __restrict__ b2,
    const bf16*  __restrict__ wt3,  // [256][256] bf16(Wout^T)
    const float* __restrict__ bout,
    const int*   __restrict__ aid2,
    float* __restrict__ out)        // [B][256] fp32
{
    __shared__ __align__(16) bf16 hs[RMB][BHSTR];   // 33792 B (h1 tile, then h2)
    __shared__ __align__(16) bf16 ws[HDIM][BSTR];   // 36864 B

    const int tid  = threadIdx.x;
    const int lane = tid & 63;
    const int wave = tid >> 6;
    const int l15  = lane & 15;
    const int quad = lane >> 4;
    const size_t row0 = (size_t)blockIdx.x * RMB;

    // load h1 tile once: 64x256 bf16 = 2048 chunk8, 8/thread
    #pragma unroll
    for (int p = 0; p < 8; ++p) {
        int c = tid + p * 256;
        int r = c >> 5, q = c & 31;
        *(bf16x8*)&hs[r][q * 8] = *(const bf16x8*)(h1 + (row0 + r) * HDIM + q * 8);
    }

    f32x4 acc[4][4];

    // ---- GEMM2 ----
    #pragma unroll
    for (int i = 0; i < 4; ++i)
        #pragma unroll
        for (int j = 0; j < 4; ++j)
            acc[i][j] = (f32x4){0.f, 0.f, 0.f, 0.f};

    for (int kt = 0; kt < HDIM / BKB; ++kt) {
        const int k0 = kt * BKB;
        #pragma unroll
        for (int p = 0; p < 8; ++p) {
            int c = tid + p * 256;
            int n = c >> 3, q = c & 7;
            *(bf16x8*)&ws[n][q * 8] =
                *(const bf16x8*)(wt2 + (size_t)n * HDIM + k0 + q * 8);
        }
        __syncthreads();   // also orders the h1-tile (kt=0) / h2 writes
        #pragma unroll
        for (int s = 0; s < 2; ++s) {
            bf16x8 afr[4];
            #pragma unroll
            for (int i = 0; i < 4; ++i)
                afr[i] = *(const bf16x8*)&hs[i * 16 + l15][k0 + s * 32 + quad * 8];
            #pragma unroll
            for (int j = 0; j < 4; ++j) {
                bf16x8 bfr = *(const bf16x8*)&ws[wave * 64 + j * 16 + l15][s * 32 + quad * 8];
                #pragma unroll
                for (int i = 0; i < 4; ++i)
                    acc[i][j] = __builtin_amdgcn_mfma_f32_16x16x32_bf16(afr[i], bfr, acc[i][j], 0, 0, 0);
            }
        }
        __syncthreads();
    }
    // epilogue: h2 = act(. + b2) -> hs (all hs reads retired before final barrier)
    #pragma unroll
    for (int j = 0; j < 4; ++j) {
        int col = wave * 64 + j * 16 + l15;
        float bias = b2[col];
        int aid = aid2[col];
        #pragma unroll
        for (int i = 0; i < 4; ++i)
            #pragma unroll
            for (int r = 0; r < 4; ++r) {
                int row = i * 16 + quad * 4 + r;
                hs[row][col] = (bf16)het_act(acc[i][j][r] + bias, aid);
            }
    }

    // ---- GEMM3 ----
    #pragma unroll
    for (int i = 0; i < 4; ++i)
        #pragma unroll
        for (int j = 0; j < 4; ++j)
            acc[i][j] = (f32x4){0.f, 0.f, 0.f, 0.f};

    for (int kt = 0; kt < HDIM / BKB; ++kt) {
        const int k0 = kt * BKB;
        #pragma unroll
        for (int p = 0; p < 8; ++p) {
            int c = tid + p * 256;
            int n = c >> 3, q = c & 7;
            *(bf16x8*)&ws[n][q * 8] =
                *(const bf16x8*)(wt3 + (size_t)n * HDIM + k0 + q * 8);
        }
        __syncthreads();   // orders h2 writes before reads
        #pragma unroll
        for (int s = 0; s < 2; ++s) {
            bf16x8 afr[4];
            #pragma unroll
            for (int i = 0; i < 4; ++i)
                afr[i] = *(const bf16x8*)&hs[i * 16 + l15][k0 + s * 32 + quad * 8];
            #pragma unroll
            for (int j = 0; j < 4; ++j) {
                bf16x8 bfr = *(const bf16x8*)&ws[wave * 64 + j * 16 + l15][s * 32 + quad * 8];
                #pragma unroll
                for (int i = 0; i < 4; ++i)
                    acc[i][j] = __builtin_amdgcn_mfma_f32_16x16x32_bf16(afr[i], bfr, acc[i][j], 0, 0, 0);
            }
        }
        __syncthreads();
    }
    // epilogue: fp32 store (lanes 0-15 contiguous 64B runs)
    #pragma unroll
    for (int j = 0; j < 4; ++j) {
        int col = wave * 64 + j * 16 + l15;
        float bias = bout[col];
        #pragma unroll
        for (int i = 0; i < 4; ++i)
            #pragma unroll
            for (int r = 0; r < 4; ++r) {
                int row = i * 16 + quad * 4 + r;
                out[(row0 + row) * HDIM + col] = acc[i][j][r] + bias;
            }
    }
}

// =====================================================================
// Fallback: round-2 fused kernel (used only if ws_size can't hold h1)
// =====================================================================
#define FRM 64
#define FAPAD 40
#define FHPAD 264

__global__ __launch_bounds__(256, 2) void hetnet_fused(
    const float* __restrict__ x, const bf16* __restrict__ wt1, const float* __restrict__ b1,
    const bf16* __restrict__ wt2, const float* __restrict__ b2,
    const bf16* __restrict__ wt3, const float* __restrict__ bout,
    const int* __restrict__ aid1, const int* __restrict__ aid2, float* __restrict__ out)
{
    __shared__ __align__(16) bf16 hs[FRM][FHPAD];
    __shared__ __align__(16) bf16 as[FRM][FAPAD];
    __shared__ __align__(16) bf16 ws[HDIM][FAPAD];

    const int tid = threadIdx.x, lane = tid & 63, wave = tid >> 6;
    const int l15 = lane & 15, quad = lane >> 4;
    const size_t row0 = (size_t)blockIdx.x * FRM;
    f32x4 acc[4][4];

    #pragma unroll
    for (int i = 0; i < 4; ++i)
        #pragma unroll
        for (int j = 0; j < 4; ++j) acc[i][j] = (f32x4){0.f,0.f,0.f,0.f};
    for (int kt = 0; kt < K1 / 32; ++kt) {
        const int k0 = kt * 32;
        { int r = tid >> 2, q = tid & 3;
          const float* xp = x + (row0 + r) * K1 + k0 + q * 8;
          float4 f0 = *(const float4*)xp; float4 f1 = *(const float4*)(xp + 4);
          bf16x8 v; v[0]=(bf16)f0.x; v[1]=(bf16)f0.y; v[2]=(bf16)f0.z; v[3]=(bf16)f0.w;
          v[4]=(bf16)f1.x; v[5]=(bf16)f1.y; v[6]=(bf16)f1.z; v[7]=(bf16)f1.w;
          *(bf16x8*)&as[r][q * 8] = v; }
        #pragma unroll
        for (int p = 0; p < 4; ++p) {
            int c = tid + p * 256, n = c >> 2, q = c & 3;
            *(bf16x8*)&ws[n][q * 8] = *(const bf16x8*)(wt1 + (size_t)n * K1 + k0 + q * 8);
        }
        __syncthreads();
        bf16x8 afr[4];
        #pragma unroll
        for (int i = 0; i < 4; ++i) afr[i] = *(const bf16x8*)&as[i*16 + l15][quad*8];
        #pragma unroll
        for (int j = 0; j < 4; ++j) {
            bf16x8 bfr = *(const bf16x8*)&ws[wave*64 + j*16 + l15][quad*8];
            #pragma unroll
            for (int i = 0; i < 4; ++i)
                acc[i][j] = __builtin_amdgcn_mfma_f32_16x16x32_bf16(afr[i], bfr, acc[i][j], 0,0,0);
        }
        __syncthreads();
    }
    #pragma unroll
    for (int j = 0; j < 4; ++j) {
        int col = wave*64 + j*16 + l15; float bias = b1[col]; int aid = aid1[col];
        #pragma unroll
        for (int i = 0; i < 4; ++i)
            #pragma unroll
            for (int r = 0; r < 4; ++r)
                hs[i*16 + quad*4 + r][col] = (bf16)het_act(acc[i][j][r] + bias, aid);
    }
    const bf16* wts[2] = {wt2, wt3};
    for (int g = 0; g < 2; ++g) {
        #pragma unroll
        for (int i = 0; i < 4; ++i)
            #pragma unroll
            for (int j = 0; j < 4; ++j) acc[i][j] = (f32x4){0.f,0.f,0.f,0.f};
        for (int kt = 0; kt < HDIM / 32; ++kt) {
            const int k0 = kt * 32;
            #pragma unroll
            for (int p = 0; p < 4; ++p) {
                int c = tid + p * 256, n = c >> 2, q = c & 3;
                *(bf16x8*)&ws[n][q * 8] = *(const bf16x8*)(wts[g] + (size_t)n * HDIM + k0 + q * 8);
            }
            __syncthreads();
            bf16x8 afr[4];
            #pragma unroll
            for (int i = 0; i < 4; ++i) afr[i] = *(const bf16x8*)&hs[i*16 + l15][k0 + quad*8];
            #pragma unroll
            for (int j = 0; j < 4; ++j) {
                bf16x8 bfr = *(const bf16x8*)&ws[wave*64 + j*16 + l15][quad*8];
                #pragma unroll
                for (int i = 0; i < 4; ++i)
                    acc[i][j] = __builtin_amdgcn_mfma_f32_16x16x32_bf16(afr[i], bfr, acc[i][j], 0,0,0);
            }
            __syncthreads();
        }
        if (g == 0) {
            #pragma unroll
            for (int j = 0; j < 4; ++j) {
                int col = wave*64 + j*16 + l15; float bias = b2[col]; int aid = aid2[col];
                #pragma unroll
                for (int i = 0; i < 4; ++i)
                    #pragma unroll
                    for (int r = 0; r < 4; ++r)
                        hs[i*16 + quad*4 + r][col] = (bf16)het_act(acc[i][j][r] + bias, aid);
            }
        } else {
            #pragma unroll
            for (int j = 0; j < 4; ++j) {
                int col = wave*64 + j*16 + l15; float bias = bout[col];
                #pragma unroll
                for (int i = 0; i < 4; ++i)
                    #pragma unroll
                    for (int r = 0; r < 4; ++r)
                        out[(row0 + i*16 + quad*4 + r) * HDIM + col] = acc[i][j][r] + bias;
            }
        }
    }
}

extern "C" void kernel_launch(void* const* d_in, const int* in_sizes, int n_in,
                              void* d_out, int out_size, void* d_ws, size_t ws_size,
                              hipStream_t stream) {
    const float* x    = (const float*)d_in[0];
    const float* W1   = (const float*)d_in[1];
    const float* b1   = (const float*)d_in[2];
    const float* W2   = (const float*)d_in[3];
    const float* b2   = (const float*)d_in[4];
    const float* Wout = (const float*)d_in[5];
    const float* bout = (const float*)d_in[6];
    const int*   aid1 = (const int*)d_in[7];
    const int*   aid2 = (const int*)d_in[8];
    float* out = (float*)d_out;

    bf16* wt1 = (bf16*)d_ws;                       // 256*1024
    bf16* wt2 = wt1 + 256 * 1024;                  // 256*256
    bf16* wt3 = wt2 + 256 * 256;                   // 256*256
    bf16* h1  = wt3 + 256 * 256;                   // 131072*256 bf16 = 67.1 MB

    const size_t need = (size_t)(256 * 1024 + 2 * 256 * 256) * 2
                      + (size_t)BATCH * HDIM * 2;

    prep_w<<<(K1 * HDIM + 255) / 256, 256, 0, stream>>>(W1, wt1, K1 * HDIM, 10, HDIM);
    prep_w<<<(HDIM * HDIM + 255) / 256, 256, 0, stream>>>(W2, wt2, HDIM * HDIM, 8, HDIM);
    prep_w<<<(HDIM * HDIM + 255) / 256, 256, 0, stream>>>(Wout, wt3, HDIM * HDIM, 8, HDIM);

    if (ws_size >= need) {
        gemm1_kernel<<<BATCH / RMA, 512, 0, stream>>>(x, wt1, b1, aid1, h1);
        gemm23_kernel<<<BATCH / RMB, 256, 0, stream>>>(h1, wt2, b2, wt3, bout, aid2, out);
    } else {
        hetnet_fused<<<BATCH / FRM, 256, 0, stream>>>(x, wt1, b1, wt2, b2, wt3, bout,
                                                      aid1, aid2, out);
    }
}